// Round 1
// 430.764 us; speedup vs baseline: 1.1030x; 1.1030x over previous
//
#include <hip/hip_runtime.h>
#include <stdint.h>
#include <stddef.h>

// ---------------------------------------------------------------------------
// MultiHeadAttention forward, MI355X gfx950.  I/O fp32 (mask int32).
//   conv_w4: all 4 weights fp32->bf16 (one launch)
//   mask_pack: mask -> 1 bit/key (u64 words)
//   gemm_qkv (fused, grid z=0,1,2):
//     z=0: Q = (q @ wq^T + bq)*0.125*log2e -> Qp [B,H,S,64]
//     z=1: K                               -> Kp [B,H,S,64]
//     z=2: V^T                             -> Vtp [B,H,64,S]
//   attn:  X = softmax(mask(QK^T))V  (transposed S^T/O^T structure)
//   gemm_out: out = X @ wo^T + bo -> fp32
// All K-loops: double-buffered LDS, ONE barrier per tile, loads for tile t+1
// issued before tile t's MFMA phase (T3-minimum 2-phase pattern).
// XCD swizzle: grids arranged so blocks sharing the big operand share id%8.
// ---------------------------------------------------------------------------

typedef unsigned short ushort_t;
typedef unsigned long long u64;
typedef __attribute__((ext_vector_type(8))) short short8;   // 8 bf16 = 4 VGPRs
typedef __attribute__((ext_vector_type(4))) float floatx4;  // MFMA C/D
typedef __attribute__((ext_vector_type(4))) unsigned short ushort4v;
typedef __attribute__((ext_vector_type(4))) unsigned int uint4v;

#define QSCALE (0.125f * 1.4426950408889634f)  // 1/sqrt(64) * log2(e)

__device__ __forceinline__ ushort_t f2bf(float f) {          // RNE
    union { float ff; unsigned int i; } v; v.ff = f;
    unsigned int u = v.i;
    return (ushort_t)((u + 0x7fffu + ((u >> 16) & 1u)) >> 16);
}
// hardware packed fp32x2 -> bf16x2 (1 VALU op instead of ~5)
__device__ __forceinline__ unsigned int pk2(float a, float b) {
    unsigned int r;
    asm("v_cvt_pk_bf16_f32 %0, %1, %2" : "=v"(r) : "v"(a), "v"(b));
    return r;
}
__device__ __forceinline__ float fexp2(float x) {
#if __has_builtin(__builtin_amdgcn_exp2f)
    return __builtin_amdgcn_exp2f(x);
#else
    return exp2f(x);
#endif
}
// async global->LDS, 16B/lane. LDS dest = wave-uniform base + lane*16.
__device__ __forceinline__ void g2l16(const void* g, void* l) {
    __builtin_amdgcn_global_load_lds(
        (const __attribute__((address_space(1))) void*)(uintptr_t)g,
        (__attribute__((address_space(3))) void*)(uint32_t)(uintptr_t)l,
        16, 0, 0);
}

// ---------------------------------------------------------------------------
// all four weight matrices fp32 -> bf16, one launch. grid (1024, 4).
__global__ __launch_bounds__(256) void conv_w4(
    const float* __restrict__ w0, const float* __restrict__ w1,
    const float* __restrict__ w2, const float* __restrict__ w3,
    ushort_t* __restrict__ out)
{
    const int seg = blockIdx.y;
    const float* src = (seg == 0) ? w0 : (seg == 1) ? w1 : (seg == 2) ? w2 : w3;
    const int i = blockIdx.x * 256 + threadIdx.x;
    const float4 v = ((const float4*)src)[i];
    ushort4v o;
    o.x = f2bf(v.x); o.y = f2bf(v.y); o.z = f2bf(v.z); o.w = f2bf(v.w);
    ((ushort4v*)(out + (size_t)seg * 1024 * 1024))[i] = o;
}

// mask int32 [B*S*S] -> 1 bit per element, wave-ballot packed.
__global__ __launch_bounds__(256) void mask_pack(
    const int* __restrict__ m, u64* __restrict__ out)
{
    const int gid = blockIdx.x * 256 + threadIdx.x;
    const u64 bits = __ballot(m[gid] != 0);
    if ((threadIdx.x & 63) == 0) out[gid >> 6] = bits;
}

// ---------------------------------------------------------------------------
// GEMM core: C[m,n] = (sum_k A[m,k]*W[n,k] + bias[n]) * scale.  W bf16.
// M=8192, N=K=1024. Tile 128x128, BK=32, 4 waves each 64x64 (4x4 frags).
// Double-buffered LDS, one barrier per K-tile, prefetch issued pre-MFMA.
// AF32=1: A fp32, converted in-reg (pk2) after MFMA, written to next buffer.
// mode (runtime, uniform): 0 fp32 [M,N]; 1 bf16 [B,H,S,64]; 2 bf16 [B,H,64,S]
// ---------------------------------------------------------------------------
template <int AF32>
__device__ __forceinline__ void gemm_core(
    const void* __restrict__ Ain, const ushort_t* __restrict__ W,
    const float* __restrict__ bias, void* __restrict__ Cout,
    float scale, int mode)
{
    constexpr int N = 1024, K = 1024;
    __shared__ alignas(16) ushort_t As[2][128 * 32];
    __shared__ alignas(16) ushort_t Bs[2][128 * 32];

    const int tid  = threadIdx.x;
    const int lane = tid & 63;
    const int w    = tid >> 6;
    const int quad = lane >> 4;
    const int l16  = lane & 15;
    const int wm = w >> 1, wn = w & 1;
    const int bm = blockIdx.x * 128, bn = blockIdx.y * 128;

    // bf16 staging geometry (16B chunk c -> row=c>>2, chunk col (c&3)^(row&3))
    const int ar0 = tid >> 2,         acs0 = ((tid & 3) ^ (ar0 & 3)) * 8;
    const int ar1 = (tid + 256) >> 2, acs1 = ((tid & 3) ^ (ar1 & 3)) * 8;

    const ushort_t* Wst0 = W + (size_t)(bn + ar0) * K + acs0;
    const ushort_t* Wst1 = W + (size_t)(bn + ar1) * K + acs1;

    // fp32 A staging: thread t -> row=t>>1, k-half=(t&1)*16
    const int arow = tid >> 1, ahalf = tid & 1;
    const float* Af = (const float*)Ain + (size_t)(bm + arow) * K + ahalf * 16;
    const int ac0 = ((2 * ahalf + 0) ^ (arow & 3)) * 8;   // swizzled chunk cols
    const int ac1 = ((2 * ahalf + 1) ^ (arow & 3)) * 8;

    // bf16 A staging bases (AF32=0)
    const ushort_t* Ast0 = (const ushort_t*)Ain + (size_t)(bm + ar0) * K + acs0;
    const ushort_t* Ast1 = (const ushort_t*)Ain + (size_t)(bm + ar1) * K + acs1;

    // frag-read offsets (loop-invariant)
    const int ksw = (quad ^ (l16 & 3)) * 8;
    int asoff[4], bsoff[4];
#pragma unroll
    for (int i = 0; i < 4; i++) {
        asoff[i] = (wm * 64 + i * 16 + l16) * 32 + ksw;
        bsoff[i] = (wn * 64 + i * 16 + l16) * 32 + ksw;
    }

    floatx4 acc[4][4] = {};

    // ---- prologue: stage kt=0 into buffer 0 ----
    if (AF32) {
        const float4* ap = (const float4*)Af;
        const float4 f0 = ap[0], f1 = ap[1], f2 = ap[2], f3 = ap[3];
        uint4v c0, c1;
        c0.x = pk2(f0.x, f0.y); c0.y = pk2(f0.z, f0.w);
        c0.z = pk2(f1.x, f1.y); c0.w = pk2(f1.z, f1.w);
        c1.x = pk2(f2.x, f2.y); c1.y = pk2(f2.z, f2.w);
        c1.z = pk2(f3.x, f3.y); c1.w = pk2(f3.z, f3.w);
        *(uint4v*)&As[0][arow * 32 + ac0] = c0;
        *(uint4v*)&As[0][arow * 32 + ac1] = c1;
    } else {
        g2l16(Ast0, &As[0][tid * 8]);
        g2l16(Ast1, &As[0][(tid + 256) * 8]);
    }
    g2l16(Wst0, &Bs[0][tid * 8]);
    g2l16(Wst1, &Bs[0][(tid + 256) * 8]);
    __syncthreads();   // drains vmcnt: buffer 0 ready

    int cur = 0;
    for (int kt = 0; kt < K; kt += 32) {
        const int nxt = kt + 32;
        float4 f0, f1, f2, f3;
        // ---- issue next-tile loads BEFORE compute (latency hides under MFMA)
        if (nxt < K) {
            if (AF32) {
                const float4* ap = (const float4*)(Af + nxt);
                f0 = ap[0]; f1 = ap[1]; f2 = ap[2]; f3 = ap[3];
            } else {
                g2l16(Ast0 + nxt, &As[cur ^ 1][tid * 8]);
                g2l16(Ast1 + nxt, &As[cur ^ 1][(tid + 256) * 8]);
            }
            g2l16(Wst0 + nxt, &Bs[cur ^ 1][tid * 8]);
            g2l16(Wst1 + nxt, &Bs[cur ^ 1][(tid + 256) * 8]);
        }

        // ---- compute from buffer cur ----
        short8 af[4], bf[4];
#pragma unroll
        for (int i = 0; i < 4; i++) af[i] = *(const short8*)&As[cur][asoff[i]];
#pragma unroll
        for (int i = 0; i < 4; i++) bf[i] = *(const short8*)&Bs[cur][bsoff[i]];
#pragma unroll
        for (int mi = 0; mi < 4; mi++)
#pragma unroll
            for (int ni = 0; ni < 4; ni++)
                acc[mi][ni] = __builtin_amdgcn_mfma_f32_16x16x32_bf16(
                    af[mi], bf[ni], acc[mi][ni], 0, 0, 0);

        // ---- convert+write prefetched A (AF32): vmem wait lands after MFMA
        if (AF32 && nxt < K) {
            uint4v c0, c1;
            c0.x = pk2(f0.x, f0.y); c0.y = pk2(f0.z, f0.w);
            c0.z = pk2(f1.x, f1.y); c0.w = pk2(f1.z, f1.w);
            c1.x = pk2(f2.x, f2.y); c1.y = pk2(f2.z, f2.w);
            c1.z = pk2(f3.x, f3.y); c1.w = pk2(f3.z, f3.w);
            *(uint4v*)&As[cur ^ 1][arow * 32 + ac0] = c0;
            *(uint4v*)&As[cur ^ 1][arow * 32 + ac1] = c1;
        }
        __syncthreads();   // next buffer fully staged, cur free for overwrite
        cur ^= 1;
    }

    // epilogue: C/D layout col=lane&15, row=quad*4+reg
#pragma unroll
    for (int ni = 0; ni < 4; ni++) {
        const int n = bn + wn * 64 + ni * 16 + l16;
        const float bv_ = bias[n];
#pragma unroll
        for (int mi = 0; mi < 4; mi++) {
            const int mbase = bm + wm * 64 + mi * 16 + quad * 4;
            if (mode == 2) {
                const int b_ = mbase >> 11, s0 = mbase & 2047;
                const int h = n >> 6, d = n & 63;
                ushort4v pk_;
#pragma unroll
                for (int r = 0; r < 4; r++)
                    pk_[r] = f2bf((acc[mi][ni][r] + bv_) * scale);
                *(ushort4v*)&((ushort_t*)Cout)[
                    (((size_t)(b_ * 16 + h)) * 64 + d) * 2048 + s0] = pk_;
            } else {
#pragma unroll
                for (int r = 0; r < 4; r++) {
                    const int m = mbase + r;
                    const float of = (acc[mi][ni][r] + bv_) * scale;
                    if (mode == 0) {
                        ((float*)Cout)[(size_t)m * N + n] = of;
                    } else {
                        const int b_ = m >> 11, s = m & 2047;
                        const int h = n >> 6, d = n & 63;
                        ((ushort_t*)Cout)[(((size_t)(b_ * 16 + h)) * 2048 + s) * 64 + d]
                            = f2bf(of);
                    }
                }
            }
        }
    }
}

// fused QKV projections. grid (64, 8, 3): x = M-tile (id%8 XCD/L2 A reuse).
__global__ __launch_bounds__(256, 2) void gemm_qkv(
    const float* __restrict__ q, const float* __restrict__ k,
    const float* __restrict__ v, const ushort_t* __restrict__ Wb,
    const float* __restrict__ bq, const float* __restrict__ bk,
    const float* __restrict__ bv,
    ushort_t* __restrict__ Qp, ushort_t* __restrict__ Kp,
    ushort_t* __restrict__ Vtp)
{
    const int z = blockIdx.z;
    const float* A = (z == 0) ? q : (z == 1) ? k : v;
    const ushort_t* W = Wb + (size_t)z * 1024 * 1024;
    const float* bi = (z == 0) ? bq : (z == 1) ? bk : bv;
    void* C = (z == 0) ? (void*)Qp : (z == 1) ? (void*)Kp : (void*)Vtp;
    const float sc = (z == 0) ? QSCALE : 1.0f;
    const int mode = (z == 2) ? 2 : 1;
    gemm_core<1>(A, W, bi, C, sc, mode);
}

// output projection: X bf16 via global_load_lds, fp32 out.
__global__ __launch_bounds__(256, 2) void gemm_out(
    const ushort_t* __restrict__ X, const ushort_t* __restrict__ W,
    const float* __restrict__ bo, float* __restrict__ out)
{
    gemm_core<0>(X, W, bo, out, 1.0f, 0);
}

// ---------------------------------------------------------------------------
// Flash attention, transposed: S^T = K Q^T so C-layout lane = q, regs = 4
// consecutive keys. P packed to LDS via ds_write_b64; O^T = V^T P; l via
// ones-MFMA (per-lane scalar). No-max softmax (Q pre-scaled into log2 domain).
// Double-buffered K/V LDS (40 KB -> 4 blocks/CU), one barrier per kt,
// next tile's g2l16 issued before this tile's MFMA phase.
// grid (64, 32): blockIdx.x = bh -> same-bh blocks share id%8 (K/V L2 reuse).
// ---------------------------------------------------------------------------
__global__ __launch_bounds__(256, 4) void attn(
    const ushort_t* __restrict__ Q,   // [B*H, S, 64] (log2-domain scale)
    const ushort_t* __restrict__ Kk,  // [B*H, S, 64]
    const ushort_t* __restrict__ Vt,  // [B*H, 64, S]
    const u64* __restrict__ mb,       // [B, S, 32] bit-packed mask
    ushort_t* __restrict__ X)         // [B, S, H*64]
{
    constexpr int S = 2048;
    __shared__ alignas(16) ushort_t Ks[2][64 * 64];
    __shared__ alignas(16) ushort_t Vs[2][64 * 64];
    __shared__ alignas(16) ushort_t Ps[4][16 * 64];

    const int tid  = threadIdx.x;
    const int lane = tid & 63;
    const int w    = tid >> 6;
    const int quad = lane >> 4;
    const int l16  = lane & 15;
    const int bh = blockIdx.x;          // 0..63  (id%8 = bh%8 -> XCD locality)
    const int b  = bh >> 4, h = bh & 15;
    const int qbase = blockIdx.y * 64 + w * 16;
    const int qlane = qbase + l16;      // this lane's q row

    // staging geometry for 64x64 bf16 tiles (8 chunks/row, XOR-swizzled)
    const int r0 = tid >> 3,         cs0 = ((tid & 7) ^ (r0 & 7)) * 8;
    const int r1 = (tid + 256) >> 3, cs1 = ((tid & 7) ^ (r1 & 7)) * 8;

    const ushort_t* Kst0 = &Kk[((size_t)bh * S + r0) * 64 + cs0];  // +kt*4096
    const ushort_t* Kst1 = &Kk[((size_t)bh * S + r1) * 64 + cs1];
    const ushort_t* Vst0 = &Vt[((size_t)bh * 64 + r0) * S + cs0];  // +kt*64
    const ushort_t* Vst1 = &Vt[((size_t)bh * 64 + r1) * S + cs1];

    // loop-invariant LDS offsets
    const int swz = l16 & 7;
    int kvoff[2][4], pfoff[2], pwoff[4];
#pragma unroll
    for (int ks = 0; ks < 2; ks++) {
        pfoff[ks] = l16 * 64 + (((ks * 4 + quad) ^ swz) * 8);
#pragma unroll
        for (int ni = 0; ni < 4; ni++)
            kvoff[ks][ni] = (ni * 16 + l16) * 64 + (((ks * 4 + quad) ^ swz) * 8);
    }
#pragma unroll
    for (int ni = 0; ni < 4; ni++)   // P write: row=l16(q), 4 consec keys, 8B
        pwoff[ni] = l16 * 64 + (((ni * 2 + (quad >> 1)) ^ swz) * 8) + (quad & 1) * 4;
    ushort_t* Psw = &Ps[w][0];

    // Q fragments (B-operand) resident for whole kernel
    short8 qf[2];
#pragma unroll
    for (int ks = 0; ks < 2; ks++)
        qf[ks] = *(const short8*)&Q[((size_t)bh * S + qlane) * 64 + ks * 32 + quad * 8];

    short8 onesv;
#pragma unroll
    for (int i = 0; i < 8; i++) onesv[i] = (short)0x3F80;  // bf16 1.0

    const u64* mrow = mb + ((size_t)b * S + qlane) * 32;   // one u64 per tile

    floatx4 o[4] = {};
    floatx4 lf = {};

    // prologue: stage kt=0 into buffer 0
    g2l16(Kst0, &Ks[0][tid * 8]);
    g2l16(Kst1, &Ks[0][(tid + 256) * 8]);
    g2l16(Vst0, &Vs[0][tid * 8]);
    g2l16(Vst1, &Vs[0][(tid + 256) * 8]);
    __syncthreads();

    int cur = 0;
    for (int kt = 0; kt < 32; kt++) {
        // issue next K/V tile into the other buffer (hidden under compute)
        if (kt < 31) {
            g2l16(Kst0 + (kt + 1) * 4096, &Ks[cur ^ 1][tid * 8]);
            g2l16(Kst1 + (kt + 1) * 4096, &Ks[cur ^ 1][(tid + 256) * 8]);
            g2l16(Vst0 + (kt + 1) * 64,   &Vs[cur ^ 1][tid * 8]);
            g2l16(Vst1 + (kt + 1) * 64,   &Vs[cur ^ 1][(tid + 256) * 8]);
        }
        const ushort_t* Ksc = &Ks[cur][0];
        const ushort_t* Vsc = &Vs[cur][0];

        // S^T = K Q^T: A = K-frag (rows=key), B = Q-frag (rows=q)
        floatx4 s[4] = {};
#pragma unroll
        for (int ks = 0; ks < 2; ks++)
#pragma unroll
            for (int ni = 0; ni < 4; ni++)
                s[ni] = __builtin_amdgcn_mfma_f32_16x16x32_bf16(
                    *(const short8*)&Ksc[kvoff[ks][ni]], qf[ks], s[ni], 0, 0, 0);

        // p = mask ? exp2(s) : 0   (lane q fixed; reg r = key quad*4+r+16ni)
        const u64 mw = mrow[kt];
#pragma unroll
        for (int ni = 0; ni < 4; ni++) {
            const unsigned int t = (unsigned int)(mw >> (ni * 16 + quad * 4));
#pragma unroll
            for (int r = 0; r < 4; r++)
                s[ni][r] = (t & (1u << r)) ? fexp2(s[ni][r]) : 0.f;
        }

        // P -> LDS: per ni pack 4 consecutive keys -> one ds_write_b64
#pragma unroll
        for (int ni = 0; ni < 4; ni++) {
            const unsigned int lo = pk2(s[ni][0], s[ni][1]);
            const unsigned int hi = pk2(s[ni][2], s[ni][3]);
            const unsigned long long dv = ((unsigned long long)hi << 32) | lo;
            *(unsigned long long*)&Psw[pwoff[ni]] = dv;
        }

        // O^T += V^T P ; l += ones^T P
#pragma unroll
        for (int ks = 0; ks < 2; ks++) {
            const short8 pf = *(const short8*)&Psw[pfoff[ks]];
            lf = __builtin_amdgcn_mfma_f32_16x16x32_bf16(onesv, pf, lf, 0, 0, 0);
#pragma unroll
            for (int ni = 0; ni < 4; ni++)
                o[ni] = __builtin_amdgcn_mfma_f32_16x16x32_bf16(
                    *(const short8*)&Vsc[kvoff[ks][ni]], pf, o[ni], 0, 0, 0);
        }
        __syncthreads();   // buffer cur^1 fully staged; cur free for overwrite
        cur ^= 1;
    }

    // epilogue: lane holds q=qlane, d = ni*16 + quad*4 + r (consecutive -> 8B store)
    const float inv = 1.0f / lf[0];
#pragma unroll
    for (int ni = 0; ni < 4; ni++) {
        ushort4v pk_;
#pragma unroll
        for (int r = 0; r < 4; r++) pk_[r] = f2bf(o[ni][r] * inv);
        *(ushort4v*)&X[((size_t)b * S + qlane) * 1024 + h * 64 + ni * 16 + quad * 4] = pk_;
    }
}

// ---------------------------------------------------------------------------
extern "C" void kernel_launch(void* const* d_in, const int* in_sizes, int n_in,
                              void* d_out, int out_size, void* d_ws, size_t ws_size,
                              hipStream_t stream) {
    const float* q    = (const float*)d_in[0];
    const float* k    = (const float*)d_in[1];
    const float* v    = (const float*)d_in[2];
    const int*   mask = (const int*)d_in[3];
    const float* wq   = (const float*)d_in[4];
    const float* bq   = (const float*)d_in[5];
    const float* wk   = (const float*)d_in[6];
    const float* bk   = (const float*)d_in[7];
    const float* wv   = (const float*)d_in[8];
    const float* bv   = (const float*)d_in[9];
    const float* wo   = (const float*)d_in[10];
    const float* bo   = (const float*)d_in[11];

    const size_t MB = 1024 * 1024;
    uint8_t* ws = (uint8_t*)d_ws;
    ushort_t* Wb   = (ushort_t*)(ws);              //  8 MB: wq,wk,wv,wo bf16
    u64*      mbits= (u64*)(ws + 8 * MB);          //  2 MB
    ushort_t* Qp   = (ushort_t*)(ws + 10 * MB);    // 16 MB
    ushort_t* Kp   = (ushort_t*)(ws + 26 * MB);    // 16 MB
    ushort_t* Vtp  = (ushort_t*)(ws + 42 * MB);    // 16 MB
    ushort_t* Xp   = (ushort_t*)(ws + 58 * MB);    // 16 MB  (total 74 MB)

    dim3 blk(256);
    const int gW = (1024 * 1024) / 1024;
    const int gM = (4 * 2048 * 2048) / 256;

    conv_w4<<<dim3(gW, 4), blk, 0, stream>>>(wq, wk, wv, wo, Wb);
    mask_pack<<<gM, blk, 0, stream>>>(mask, mbits);

    gemm_qkv<<<dim3(64, 8, 3), blk, 0, stream>>>(q, k, v, Wb, bq, bk, bv,
                                                 Qp, Kp, Vtp);

    attn<<<dim3(64, 32), blk, 0, stream>>>(Qp, Kp, Vtp, mbits, Xp);

    gemm_out<<<dim3(64, 8), blk, 0, stream>>>(Xp, Wb + 3 * MB, bo, (float*)d_out);
}

// Round 3
// 419.500 us; speedup vs baseline: 1.1327x; 1.0269x over previous
//
#include <hip/hip_runtime.h>
#include <stdint.h>
#include <stddef.h>

// ---------------------------------------------------------------------------
// MultiHeadAttention forward, MI355X gfx950.  I/O fp32 (mask int32).
//   conv_w4: all 4 weights fp32->bf16 (one launch)
//   mask_pack: mask -> 1 bit/key (u64 words), wave-ballot (proven r1 version)
//   cvt_a: q,k,v fp32 -> bf16 (one launch, grid z=0,1,2)
//   gemm_qkv (fused, grid z=0,1,2): Q/K/V projections, pure-bf16 A
//   attn:  X = softmax(mask(QK^T))V  (transposed S^T/O^T structure; r1 proven)
//   gemm_out: out = X @ wo^T + bo -> fp32
// GEMM K-loop: 3-slot LDS ring, counted vmcnt(4) (never 0 mid-loop), raw
// s_barrier. vm queue contains ONLY global_load_lds ops in per-tile groups
// of 4 -> waitcnt counts are robust to scheduling (m201/T3+T4 pattern).
// ---------------------------------------------------------------------------

typedef unsigned short ushort_t;
typedef unsigned long long u64;
typedef __attribute__((ext_vector_type(8))) short short8;   // 8 bf16 = 4 VGPRs
typedef __attribute__((ext_vector_type(4))) float floatx4;  // MFMA C/D
typedef __attribute__((ext_vector_type(4))) unsigned short ushort4v;
typedef __attribute__((ext_vector_type(4))) unsigned int uint4v;

#define QSCALE (0.125f * 1.4426950408889634f)  // 1/sqrt(64) * log2(e)

__device__ __forceinline__ ushort_t f2bf(float f) {          // RNE
    union { float ff; unsigned int i; } v; v.ff = f;
    unsigned int u = v.i;
    return (ushort_t)((u + 0x7fffu + ((u >> 16) & 1u)) >> 16);
}
// hardware packed fp32x2 -> bf16x2 (1 VALU op). Proven in r1 (attn + gemm).
__device__ __forceinline__ unsigned int pk2(float a, float b) {
    unsigned int r;
    asm("v_cvt_pk_bf16_f32 %0, %1, %2" : "=v"(r) : "v"(a), "v"(b));
    return r;
}
__device__ __forceinline__ float fexp2(float x) {
#if __has_builtin(__builtin_amdgcn_exp2f)
    return __builtin_amdgcn_exp2f(x);
#else
    return exp2f(x);
#endif
}
// async global->LDS, 16B/lane. LDS dest = wave-uniform base + lane*16.
__device__ __forceinline__ void g2l16(const void* g, void* l) {
    __builtin_amdgcn_global_load_lds(
        (const __attribute__((address_space(1))) void*)(uintptr_t)g,
        (__attribute__((address_space(3))) void*)(uint32_t)(uintptr_t)l,
        16, 0, 0);
}

// ---------------------------------------------------------------------------
// all four weight matrices fp32 -> bf16, one launch. grid (1024, 4).
__global__ __launch_bounds__(256) void conv_w4(
    const float* __restrict__ w0, const float* __restrict__ w1,
    const float* __restrict__ w2, const float* __restrict__ w3,
    ushort_t* __restrict__ out)
{
    const int seg = blockIdx.y;
    const float* src = (seg == 0) ? w0 : (seg == 1) ? w1 : (seg == 2) ? w2 : w3;
    const int i = blockIdx.x * 256 + threadIdx.x;
    const float4 v = ((const float4*)src)[i];
    ushort4v o;
    o.x = f2bf(v.x); o.y = f2bf(v.y); o.z = f2bf(v.z); o.w = f2bf(v.w);
    ((ushort4v*)(out + (size_t)seg * 1024 * 1024))[i] = o;
}

// q,k,v fp32 -> bf16 row-major. grid (4096, 3), 8 floats/thread.
__global__ __launch_bounds__(256) void cvt_a(
    const float* __restrict__ q, const float* __restrict__ k,
    const float* __restrict__ v,
    ushort_t* __restrict__ Qb, ushort_t* __restrict__ Kb,
    ushort_t* __restrict__ Vb)
{
    const int z = blockIdx.y;
    const float* src = (z == 0) ? q : (z == 1) ? k : v;
    ushort_t* dst = (z == 0) ? Qb : (z == 1) ? Kb : Vb;
    const int i = blockIdx.x * 256 + threadIdx.x;
    const float4 f0 = ((const float4*)src)[i * 2];
    const float4 f1 = ((const float4*)src)[i * 2 + 1];
    uint4v c;
    c.x = pk2(f0.x, f0.y); c.y = pk2(f0.z, f0.w);
    c.z = pk2(f1.x, f1.y); c.w = pk2(f1.z, f1.w);
    ((uint4v*)dst)[i] = c;
}

// mask int32 [B*S*S] -> 1 bit per element, wave-ballot packed. (r1 proven)
__global__ __launch_bounds__(256) void mask_pack(
    const int* __restrict__ m, u64* __restrict__ out)
{
    const int gid = blockIdx.x * 256 + threadIdx.x;
    const u64 bits = __ballot(m[gid] != 0);
    if ((threadIdx.x & 63) == 0) out[gid >> 6] = bits;
}

// ---------------------------------------------------------------------------
// GEMM core: C[m,n] = (sum_k A[m,k]*W[n,k] + bias[n]) * scale.  A,W bf16.
// M=8192, N=K=1024. Tile 128x128, BK=32, 4 waves each 64x64 (4x4 frags).
// 3-slot LDS ring, 2 tiles in flight, vmcnt(4) at iter top (tail: 4 then 0).
// Iter t: wait G(t) [G(t+1) stays in flight]; barrier; issue G(t+2) into
// slot (t+2)%3; MFMA from slot t%3.
// mode (runtime, uniform): 0 fp32 [M,N]; 1 bf16 [B,H,S,64]; 2 bf16 [B,H,64,S]
// ---------------------------------------------------------------------------
__device__ __forceinline__ void gemm_core(
    const ushort_t* __restrict__ Ain, const ushort_t* __restrict__ W,
    const float* __restrict__ bias, void* __restrict__ Cout,
    float scale, int mode)
{
    constexpr int N = 1024, K = 1024;
    __shared__ alignas(16) ushort_t As[3][128 * 32];
    __shared__ alignas(16) ushort_t Bs[3][128 * 32];

    const int tid  = threadIdx.x;
    const int lane = tid & 63;
    const int w    = tid >> 6;
    const int quad = lane >> 4;
    const int l16  = lane & 15;
    const int wm = w >> 1, wn = w & 1;
    const int bm = blockIdx.x * 128, bn = blockIdx.y * 128;

    // staging geometry (16B chunk c -> row=c>>2, chunk col (c&3)^(row&3));
    // g2l16 linear LDS dest, pre-swizzled global source (r1-proven).
    const int ar0 = tid >> 2,         acs0 = ((tid & 3) ^ (ar0 & 3)) * 8;
    const int ar1 = (tid + 256) >> 2, acs1 = ((tid & 3) ^ (ar1 & 3)) * 8;
    const ushort_t* Ast0 = Ain + (size_t)(bm + ar0) * K + acs0;
    const ushort_t* Ast1 = Ain + (size_t)(bm + ar1) * K + acs1;
    const ushort_t* Wst0 = W + (size_t)(bn + ar0) * K + acs0;
    const ushort_t* Wst1 = W + (size_t)(bn + ar1) * K + acs1;

    // frag-read offsets (loop-invariant)
    const int ksw = (quad ^ (l16 & 3)) * 8;
    int asoff[4], bsoff[4];
#pragma unroll
    for (int i = 0; i < 4; i++) {
        asoff[i] = (wm * 64 + i * 16 + l16) * 32 + ksw;
        bsoff[i] = (wn * 64 + i * 16 + l16) * 32 + ksw;
    }

    floatx4 acc[4][4] = {};

    // ---- prologue: tiles 0,1 into slots 0,1 (8 g2l16; queue depth 8) ----
    g2l16(Ast0,      &As[0][tid * 8]);
    g2l16(Ast1,      &As[0][(tid + 256) * 8]);
    g2l16(Wst0,      &Bs[0][tid * 8]);
    g2l16(Wst1,      &Bs[0][(tid + 256) * 8]);
    g2l16(Ast0 + 32, &As[1][tid * 8]);
    g2l16(Ast1 + 32, &As[1][(tid + 256) * 8]);
    g2l16(Wst0 + 32, &Bs[1][tid * 8]);
    g2l16(Wst1 + 32, &Bs[1][(tid + 256) * 8]);

#define GITER(SLOT, NSLOT, KOFF, DO_ISSUE, TOPW) do {                         \
    asm volatile("s_waitcnt " TOPW);                                          \
    asm volatile("s_waitcnt lgkmcnt(0)");                                     \
    __builtin_amdgcn_sched_barrier(0);                                        \
    __builtin_amdgcn_s_barrier();                                             \
    __builtin_amdgcn_sched_barrier(0);                                        \
    if (DO_ISSUE) {                                                           \
        g2l16(Ast0 + (KOFF), &As[NSLOT][tid * 8]);                            \
        g2l16(Ast1 + (KOFF), &As[NSLOT][(tid + 256) * 8]);                    \
        g2l16(Wst0 + (KOFF), &Bs[NSLOT][tid * 8]);                            \
        g2l16(Wst1 + (KOFF), &Bs[NSLOT][(tid + 256) * 8]);                    \
    }                                                                         \
    {                                                                         \
        short8 af[4], bf[4];                                                  \
        _Pragma("unroll")                                                     \
        for (int i = 0; i < 4; i++) af[i] = *(const short8*)&As[SLOT][asoff[i]];\
        _Pragma("unroll")                                                     \
        for (int i = 0; i < 4; i++) bf[i] = *(const short8*)&Bs[SLOT][bsoff[i]];\
        _Pragma("unroll")                                                     \
        for (int mi = 0; mi < 4; mi++)                                        \
        _Pragma("unroll")                                                     \
        for (int ni = 0; ni < 4; ni++)                                        \
            acc[mi][ni] = __builtin_amdgcn_mfma_f32_16x16x32_bf16(            \
                af[mi], bf[ni], acc[mi][ni], 0, 0, 0);                        \
    }                                                                         \
} while (0)

    // iters 0..29 (3-unrolled so ring slots are literals), tail 30, 31
    for (int j = 0; j < 10; ++j) {
        const int kt = j * 96;
        GITER(0, 2, kt + 64,  true, "vmcnt(4)");
        GITER(1, 0, kt + 96,  true, "vmcnt(4)");
        GITER(2, 1, kt + 128, true, "vmcnt(4)");
    }
    GITER(0, 0, 0, false, "vmcnt(4)");
    GITER(1, 0, 0, false, "vmcnt(0)");
#undef GITER

    // epilogue: C/D layout col=lane&15, row=quad*4+reg
#pragma unroll
    for (int ni = 0; ni < 4; ni++) {
        const int n = bn + wn * 64 + ni * 16 + l16;
        const float bv_ = bias[n];
#pragma unroll
        for (int mi = 0; mi < 4; mi++) {
            const int mbase = bm + wm * 64 + mi * 16 + quad * 4;
            if (mode == 2) {
                const int b_ = mbase >> 11, s0 = mbase & 2047;
                const int h = n >> 6, d = n & 63;
                ushort4v pk_;
#pragma unroll
                for (int r = 0; r < 4; r++)
                    pk_[r] = f2bf((acc[mi][ni][r] + bv_) * scale);
                *(ushort4v*)&((ushort_t*)Cout)[
                    (((size_t)(b_ * 16 + h)) * 64 + d) * 2048 + s0] = pk_;
            } else {
#pragma unroll
                for (int r = 0; r < 4; r++) {
                    const int m = mbase + r;
                    const float of = (acc[mi][ni][r] + bv_) * scale;
                    if (mode == 0) {
                        ((float*)Cout)[(size_t)m * N + n] = of;
                    } else {
                        const int b_ = m >> 11, s = m & 2047;
                        const int h = n >> 6, d = n & 63;
                        ((ushort_t*)Cout)[(((size_t)(b_ * 16 + h)) * 2048 + s) * 64 + d]
                            = f2bf(of);
                    }
                }
            }
        }
    }
}

// fused QKV projections, bf16 A. grid (64, 8, 3): x = M-tile (id%8 XCD reuse).
__global__ __launch_bounds__(256, 3) void gemm_qkv(
    const ushort_t* __restrict__ Qb, const ushort_t* __restrict__ Kb,
    const ushort_t* __restrict__ Vb, const ushort_t* __restrict__ Wb,
    const float* __restrict__ bq, const float* __restrict__ bk,
    const float* __restrict__ bv,
    ushort_t* __restrict__ Qp, ushort_t* __restrict__ Kp,
    ushort_t* __restrict__ Vtp)
{
    const int z = blockIdx.z;
    const ushort_t* A = (z == 0) ? Qb : (z == 1) ? Kb : Vb;
    const ushort_t* W = Wb + (size_t)z * 1024 * 1024;
    const float* bi = (z == 0) ? bq : (z == 1) ? bk : bv;
    void* C = (z == 0) ? (void*)Qp : (z == 1) ? (void*)Kp : (void*)Vtp;
    const float sc = (z == 0) ? QSCALE : 1.0f;
    const int mode = (z == 2) ? 2 : 1;
    gemm_core(A, W, bi, C, sc, mode);
}

// output projection: X bf16, fp32 out.
__global__ __launch_bounds__(256, 3) void gemm_out(
    const ushort_t* __restrict__ X, const ushort_t* __restrict__ W,
    const float* __restrict__ bo, float* __restrict__ out)
{
    gemm_core(X, W, bo, out, 1.0f, 0);
}

// ---------------------------------------------------------------------------
// Flash attention, transposed: S^T = K Q^T so C-layout lane = q, regs = 4
// consecutive keys. P packed to LDS via ds_write_b64; O^T = V^T P; l via
// ones-MFMA. No-max softmax (Q pre-scaled, log2 domain). Double-buffered K/V
// LDS, one barrier per kt, next tile's g2l16 issued before MFMA phase.
// grid (64, 32): blockIdx.x = bh -> same-bh blocks share id%8 (K/V L2 reuse).
// (byte-identical to the round-1 version that passed)
// ---------------------------------------------------------------------------
__global__ __launch_bounds__(256, 4) void attn(
    const ushort_t* __restrict__ Q,   // [B*H, S, 64] (log2-domain scale)
    const ushort_t* __restrict__ Kk,  // [B*H, S, 64]
    const ushort_t* __restrict__ Vt,  // [B*H, 64, S]
    const u64* __restrict__ mb,       // [B, S, 32] bit-packed mask
    ushort_t* __restrict__ X)         // [B, S, H*64]
{
    constexpr int S = 2048;
    __shared__ alignas(16) ushort_t Ks[2][64 * 64];
    __shared__ alignas(16) ushort_t Vs[2][64 * 64];
    __shared__ alignas(16) ushort_t Ps[4][16 * 64];

    const int tid  = threadIdx.x;
    const int lane = tid & 63;
    const int w    = tid >> 6;
    const int quad = lane >> 4;
    const int l16  = lane & 15;
    const int bh = blockIdx.x;
    const int b  = bh >> 4, h = bh & 15;
    const int qbase = blockIdx.y * 64 + w * 16;
    const int qlane = qbase + l16;

    const int r0 = tid >> 3,         cs0 = ((tid & 7) ^ (r0 & 7)) * 8;
    const int r1 = (tid + 256) >> 3, cs1 = ((tid & 7) ^ (r1 & 7)) * 8;

    const ushort_t* Kst0 = &Kk[((size_t)bh * S + r0) * 64 + cs0];  // +kt*4096
    const ushort_t* Kst1 = &Kk[((size_t)bh * S + r1) * 64 + cs1];
    const ushort_t* Vst0 = &Vt[((size_t)bh * 64 + r0) * S + cs0];  // +kt*64
    const ushort_t* Vst1 = &Vt[((size_t)bh * 64 + r1) * S + cs1];

    const int swz = l16 & 7;
    int kvoff[2][4], pfoff[2], pwoff[4];
#pragma unroll
    for (int ks = 0; ks < 2; ks++) {
        pfoff[ks] = l16 * 64 + (((ks * 4 + quad) ^ swz) * 8);
#pragma unroll
        for (int ni = 0; ni < 4; ni++)
            kvoff[ks][ni] = (ni * 16 + l16) * 64 + (((ks * 4 + quad) ^ swz) * 8);
    }
#pragma unroll
    for (int ni = 0; ni < 4; ni++)
        pwoff[ni] = l16 * 64 + (((ni * 2 + (quad >> 1)) ^ swz) * 8) + (quad & 1) * 4;
    ushort_t* Psw = &Ps[w][0];

    short8 qf[2];
#pragma unroll
    for (int ks = 0; ks < 2; ks++)
        qf[ks] = *(const short8*)&Q[((size_t)bh * S + qlane) * 64 + ks * 32 + quad * 8];

    short8 onesv;
#pragma unroll
    for (int i = 0; i < 8; i++) onesv[i] = (short)0x3F80;  // bf16 1.0

    const u64* mrow = mb + ((size_t)b * S + qlane) * 32;

    floatx4 o[4] = {};
    floatx4 lf = {};

    g2l16(Kst0, &Ks[0][tid * 8]);
    g2l16(Kst1, &Ks[0][(tid + 256) * 8]);
    g2l16(Vst0, &Vs[0][tid * 8]);
    g2l16(Vst1, &Vs[0][(tid + 256) * 8]);
    __syncthreads();

    int cur = 0;
    for (int kt = 0; kt < 32; kt++) {
        if (kt < 31) {
            g2l16(Kst0 + (kt + 1) * 4096, &Ks[cur ^ 1][tid * 8]);
            g2l16(Kst1 + (kt + 1) * 4096, &Ks[cur ^ 1][(tid + 256) * 8]);
            g2l16(Vst0 + (kt + 1) * 64,   &Vs[cur ^ 1][tid * 8]);
            g2l16(Vst1 + (kt + 1) * 64,   &Vs[cur ^ 1][(tid + 256) * 8]);
        }
        const ushort_t* Ksc = &Ks[cur][0];
        const ushort_t* Vsc = &Vs[cur][0];

        floatx4 s[4] = {};
#pragma unroll
        for (int ks = 0; ks < 2; ks++)
#pragma unroll
            for (int ni = 0; ni < 4; ni++)
                s[ni] = __builtin_amdgcn_mfma_f32_16x16x32_bf16(
                    *(const short8*)&Ksc[kvoff[ks][ni]], qf[ks], s[ni], 0, 0, 0);

        const u64 mw = mrow[kt];
#pragma unroll
        for (int ni = 0; ni < 4; ni++) {
            const unsigned int t = (unsigned int)(mw >> (ni * 16 + quad * 4));
#pragma unroll
            for (int r = 0; r < 4; r++)
                s[ni][r] = (t & (1u << r)) ? fexp2(s[ni][r]) : 0.f;
        }

#pragma unroll
        for (int ni = 0; ni < 4; ni++) {
            const unsigned int lo = pk2(s[ni][0], s[ni][1]);
            const unsigned int hi = pk2(s[ni][2], s[ni][3]);
            const unsigned long long dv = ((unsigned long long)hi << 32) | lo;
            *(unsigned long long*)&Psw[pwoff[ni]] = dv;
        }

#pragma unroll
        for (int ks = 0; ks < 2; ks++) {
            const short8 pf = *(const short8*)&Psw[pfoff[ks]];
            lf = __builtin_amdgcn_mfma_f32_16x16x32_bf16(onesv, pf, lf, 0, 0, 0);
#pragma unroll
            for (int ni = 0; ni < 4; ni++)
                o[ni] = __builtin_amdgcn_mfma_f32_16x16x32_bf16(
                    *(const short8*)&Vsc[kvoff[ks][ni]], pf, o[ni], 0, 0, 0);
        }
        __syncthreads();
        cur ^= 1;
    }

    const float inv = 1.0f / lf[0];
#pragma unroll
    for (int ni = 0; ni < 4; ni++) {
        ushort4v pk_;
#pragma unroll
        for (int r = 0; r < 4; r++) pk_[r] = f2bf(o[ni][r] * inv);
        *(ushort4v*)&X[((size_t)b * S + qlane) * 1024 + h * 64 + ni * 16 + quad * 4] = pk_;
    }
}

// ---------------------------------------------------------------------------
extern "C" void kernel_launch(void* const* d_in, const int* in_sizes, int n_in,
                              void* d_out, int out_size, void* d_ws, size_t ws_size,
                              hipStream_t stream) {
    const float* q    = (const float*)d_in[0];
    const float* k    = (const float*)d_in[1];
    const float* v    = (const float*)d_in[2];
    const int*   mask = (const int*)d_in[3];
    const float* wq   = (const float*)d_in[4];
    const float* bq   = (const float*)d_in[5];
    const float* wk   = (const float*)d_in[6];
    const float* bk   = (const float*)d_in[7];
    const float* wv   = (const float*)d_in[8];
    const float* bv   = (const float*)d_in[9];
    const float* wo   = (const float*)d_in[10];
    const float* bo   = (const float*)d_in[11];

    const size_t MB = 1024 * 1024;
    uint8_t* ws = (uint8_t*)d_ws;
    ushort_t* Wb   = (ushort_t*)(ws);              //  8 MB: wq,wk,wv,wo bf16
    u64*      mbits= (u64*)(ws + 8 * MB);          //  2 MB
    ushort_t* Qp   = (ushort_t*)(ws + 10 * MB);    // 16 MB
    ushort_t* Kp   = (ushort_t*)(ws + 26 * MB);    // 16 MB
    ushort_t* Vtp  = (ushort_t*)(ws + 42 * MB);    // 16 MB
    ushort_t* Xp   = (ushort_t*)(ws + 58 * MB);    // 16 MB (Xp after attn)
    ushort_t* Qb   = (ushort_t*)(ws + 58 * MB);    // 16 MB (dead before attn)
    ushort_t* Kb   = (ushort_t*)(ws + 74 * MB);    // 16 MB
    ushort_t* Vb   = (ushort_t*)(ws + 90 * MB);    // 16 MB (total 106 MB)

    dim3 blk(256);
    const int gW = (1024 * 1024) / 1024;
    const int gM = (4 * 2048 * 2048) / 256;

    conv_w4<<<dim3(gW, 4), blk, 0, stream>>>(wq, wk, wv, wo, Wb);
    mask_pack<<<gM, blk, 0, stream>>>(mask, mbits);
    cvt_a<<<dim3(4096, 3), blk, 0, stream>>>(q, k, v, Qb, Kb, Vb);

    gemm_qkv<<<dim3(64, 8, 3), blk, 0, stream>>>(Qb, Kb, Vb, Wb, bq, bk, bv,
                                                 Qp, Kp, Vtp);

    attn<<<dim3(64, 32), blk, 0, stream>>>(Qp, Kp, Vtp, mbits, Xp);

    gemm_out<<<dim3(64, 8), blk, 0, stream>>>(Xp, Wb + 3 * MB, bo, (float*)d_out);
}

// Round 4
// 403.415 us; speedup vs baseline: 1.1778x; 1.0399x over previous
//
#include <hip/hip_runtime.h>
#include <stdint.h>
#include <stddef.h>

// ---------------------------------------------------------------------------
// MultiHeadAttention forward, MI355X gfx950.  I/O fp32 (mask int32).
//   prep: weights fp32->bf16, q/k/v fp32->bf16, mask -> 1 bit/key (1 launch)
//   gemm_qkv (fused, grid z=0,1,2): Q/K/V projections, bf16 A
//   attn:  X = softmax(mask(QK^T))V  (transposed S^T/O^T structure)
//   gemm_out: out = X @ wo^T + bo -> fp32
// GEMM K-loop: split-depth prefetch — A 4-slot ring (3 tiles deep, HBM
// latency), W 2-slot ring (1 deep, L2-hot). Counted vmcnt(2) steady-state
// (never 0 mid-loop), raw s_barrier. vm queue is ONLY global_load_lds ops,
// W-group then A-group per iter (order is count-critical, sched_barrier
// fenced).
// ---------------------------------------------------------------------------

typedef unsigned short ushort_t;
typedef unsigned long long u64;
typedef __attribute__((ext_vector_type(8))) short short8;   // 8 bf16 = 4 VGPRs
typedef __attribute__((ext_vector_type(4))) float floatx4;  // MFMA C/D
typedef __attribute__((ext_vector_type(4))) unsigned short ushort4v;
typedef __attribute__((ext_vector_type(4))) unsigned int uint4v;

#define QSCALE (0.125f * 1.4426950408889634f)  // 1/sqrt(64) * log2(e)

__device__ __forceinline__ ushort_t f2bf(float f) {          // RNE
    union { float ff; unsigned int i; } v; v.ff = f;
    unsigned int u = v.i;
    return (ushort_t)((u + 0x7fffu + ((u >> 16) & 1u)) >> 16);
}
// hardware packed fp32x2 -> bf16x2 (1 VALU op). Proven r1/r3.
__device__ __forceinline__ unsigned int pk2(float a, float b) {
    unsigned int r;
    asm("v_cvt_pk_bf16_f32 %0, %1, %2" : "=v"(r) : "v"(a), "v"(b));
    return r;
}
__device__ __forceinline__ float fexp2(float x) {
#if __has_builtin(__builtin_amdgcn_exp2f)
    return __builtin_amdgcn_exp2f(x);
#else
    return exp2f(x);
#endif
}
// async global->LDS, 16B/lane. LDS dest = wave-uniform base + lane*16.
__device__ __forceinline__ void g2l16(const void* g, void* l) {
    __builtin_amdgcn_global_load_lds(
        (const __attribute__((address_space(1))) void*)(uintptr_t)g,
        (__attribute__((address_space(3))) void*)(uint32_t)(uintptr_t)l,
        16, 0, 0);
}

// ---------------------------------------------------------------------------
// prep: one launch for all elementwise preprocessing.
//   blocks [0,2048):      weights fp32->bf16  (4 x 1M floats, 8/thread)
//   blocks [2048,14336):  q,k,v fp32->bf16    (3 x 8M floats, 8/thread)
//   blocks [14336,18432): mask -> bit-packed  (4096 ints/block, 16 ballots)
// ---------------------------------------------------------------------------
__global__ __launch_bounds__(256) void prep(
    const float* __restrict__ wq, const float* __restrict__ wk,
    const float* __restrict__ wv, const float* __restrict__ wo,
    const float* __restrict__ q, const float* __restrict__ k,
    const float* __restrict__ v, const int* __restrict__ mask,
    ushort_t* __restrict__ Wb, ushort_t* __restrict__ Qb,
    ushort_t* __restrict__ Kb, ushort_t* __restrict__ Vb,
    u64* __restrict__ mbits)
{
    const int bx = blockIdx.x, tid = threadIdx.x;
    if (bx < 14336) {   // f32 -> bf16 conversions
        const float* src; ushort_t* dst; int idx;
        if (bx < 2048) {
            const int seg = bx >> 9;     // 512 blocks per 1M-float matrix
            src = (seg == 0) ? wq : (seg == 1) ? wk : (seg == 2) ? wv : wo;
            dst = Wb + (size_t)seg * 1024 * 1024;
            idx = (bx & 511) * 256 + tid;
        } else {
            const int b2 = bx - 2048;
            const int z = b2 >> 12;      // 4096 blocks per 8M-float tensor
            src = (z == 0) ? q : (z == 1) ? k : v;
            dst = (z == 0) ? Qb : (z == 1) ? Kb : Vb;
            idx = (b2 & 4095) * 256 + tid;
        }
        const float4 f0 = ((const float4*)src)[idx * 2];
        const float4 f1 = ((const float4*)src)[idx * 2 + 1];
        uint4v c;
        c.x = pk2(f0.x, f0.y); c.y = pk2(f0.z, f0.w);
        c.z = pk2(f1.x, f1.y); c.w = pk2(f1.z, f1.w);
        ((uint4v*)dst)[idx] = c;
    } else {            // mask bit-pack, wave-ballot (r1-proven logic)
        const int b3 = bx - 14336;
        const int base = b3 * 4096;
#pragma unroll
        for (int it = 0; it < 16; ++it) {
            const int gid = base + it * 256 + tid;
            const u64 bits = __ballot(mask[gid] != 0);
            if ((tid & 63) == 0) mbits[gid >> 6] = bits;
        }
    }
}

// ---------------------------------------------------------------------------
// GEMM core: C[m,n] = (sum_k A[m,k]*W[n,k] + bias[n]) * scale.  A,W bf16.
// M=8192, N=K=1024. Tile 128x128, BK=32, 4 waves each 64x64 (4x4 frags).
// A: 4-slot LDS ring (tiles t..t+3 live).  W: 2-slot ring (t, t+1).
// Per iter t: wait vmcnt(2) [W(t) landed; A(t+2) stays in flight]; barrier;
// issue W(t+1) then A(t+3); MFMA from As[t%4], Bs[t%2].
// mode (runtime, uniform): 0 fp32 [M,N]; 1 bf16 [B,H,S,64]; 2 bf16 [B,H,64,S]
// ---------------------------------------------------------------------------
__device__ __forceinline__ void gemm_core(
    const ushort_t* __restrict__ Ain, const ushort_t* __restrict__ W,
    const float* __restrict__ bias, void* __restrict__ Cout,
    float scale, int mode)
{
    constexpr int N = 1024, K = 1024;
    __shared__ alignas(16) ushort_t As[4][128 * 32];   // 32 KB
    __shared__ alignas(16) ushort_t Bs[2][128 * 32];   // 16 KB

    const int tid  = threadIdx.x;
    const int lane = tid & 63;
    const int w    = tid >> 6;
    const int quad = lane >> 4;
    const int l16  = lane & 15;
    const int wm = w >> 1, wn = w & 1;
    const int bm = blockIdx.x * 128, bn = blockIdx.y * 128;

    // staging geometry (16B chunk c -> row=c>>2, chunk col (c&3)^(row&3));
    // g2l16 linear LDS dest, pre-swizzled global source (r1/r3-proven).
    const int ar0 = tid >> 2,         acs0 = ((tid & 3) ^ (ar0 & 3)) * 8;
    const int ar1 = (tid + 256) >> 2, acs1 = ((tid & 3) ^ (ar1 & 3)) * 8;
    const ushort_t* Ast0 = Ain + (size_t)(bm + ar0) * K + acs0;
    const ushort_t* Ast1 = Ain + (size_t)(bm + ar1) * K + acs1;
    const ushort_t* Wst0 = W + (size_t)(bn + ar0) * K + acs0;
    const ushort_t* Wst1 = W + (size_t)(bn + ar1) * K + acs1;

    // frag-read offsets (loop-invariant)
    const int ksw = (quad ^ (l16 & 3)) * 8;
    int asoff[4], bsoff[4];
#pragma unroll
    for (int i = 0; i < 4; i++) {
        asoff[i] = (wm * 64 + i * 16 + l16) * 32 + ksw;
        bsoff[i] = (wn * 64 + i * 16 + l16) * 32 + ksw;
    }

    floatx4 acc[4][4] = {};

    // ---- prologue: W(0) then A(0),A(1),A(2)  [queue: W0 A0 A1 A2] ----
    g2l16(Wst0,      &Bs[0][tid * 8]);
    g2l16(Wst1,      &Bs[0][(tid + 256) * 8]);
    __builtin_amdgcn_sched_barrier(0);
    g2l16(Ast0,      &As[0][tid * 8]);
    g2l16(Ast1,      &As[0][(tid + 256) * 8]);
    g2l16(Ast0 + 32, &As[1][tid * 8]);
    g2l16(Ast1 + 32, &As[1][(tid + 256) * 8]);
    g2l16(Ast0 + 64, &As[2][tid * 8]);
    g2l16(Ast1 + 64, &As[2][(tid + 256) * 8]);

// AS/WS: compute slots. NW/NA: issue slots. KW/KA: element offsets.
#define GITER(AS, WS, NW, NA, KW, KA, DO_W, DO_A, TOPW) do {                  \
    asm volatile("s_waitcnt " TOPW);                                          \
    asm volatile("s_waitcnt lgkmcnt(0)");                                     \
    __builtin_amdgcn_sched_barrier(0);                                        \
    __builtin_amdgcn_s_barrier();                                             \
    __builtin_amdgcn_sched_barrier(0);                                        \
    if (DO_W) {                                                               \
        g2l16(Wst0 + (KW), &Bs[NW][tid * 8]);                                 \
        g2l16(Wst1 + (KW), &Bs[NW][(tid + 256) * 8]);                         \
    }                                                                         \
    __builtin_amdgcn_sched_barrier(0);                                        \
    if (DO_A) {                                                               \
        g2l16(Ast0 + (KA), &As[NA][tid * 8]);                                 \
        g2l16(Ast1 + (KA), &As[NA][(tid + 256) * 8]);                         \
    }                                                                         \
    __builtin_amdgcn_sched_barrier(0);                                        \
    {                                                                         \
        short8 af[4], bf[4];                                                  \
        _Pragma("unroll")                                                     \
        for (int i = 0; i < 4; i++) af[i] = *(const short8*)&As[AS][asoff[i]];\
        _Pragma("unroll")                                                     \
        for (int i = 0; i < 4; i++) bf[i] = *(const short8*)&Bs[WS][bsoff[i]];\
        _Pragma("unroll")                                                     \
        for (int mi = 0; mi < 4; mi++)                                        \
        _Pragma("unroll")                                                     \
        for (int ni = 0; ni < 4; ni++)                                        \
            acc[mi][ni] = __builtin_amdgcn_mfma_f32_16x16x32_bf16(            \
                af[mi], bf[ni], acc[mi][ni], 0, 0, 0);                        \
    }                                                                         \
} while (0)

    // t = 0..3 (t=0 wait drains W0,A0 -> vmcnt(4))
    GITER(0, 0, 1, 3,  32,  96, true, true, "vmcnt(4)");
    GITER(1, 1, 0, 0,  64, 128, true, true, "vmcnt(2)");
    GITER(2, 0, 1, 1,  96, 160, true, true, "vmcnt(2)");
    GITER(3, 1, 0, 2, 128, 192, true, true, "vmcnt(2)");
    // t = 4..27, 4-unrolled so ring slots are literals
    for (int j = 1; j < 7; ++j) {
        const int kb = j * 128;
        GITER(0, 0, 1, 3, kb + 32,  kb + 96,  true, true, "vmcnt(2)");
        GITER(1, 1, 0, 0, kb + 64,  kb + 128, true, true, "vmcnt(2)");
        GITER(2, 0, 1, 1, kb + 96,  kb + 160, true, true, "vmcnt(2)");
        GITER(3, 1, 0, 2, kb + 128, kb + 192, true, true, "vmcnt(2)");
    }
    // t = 28..31 tail (A issues ended at t=28 with A(31); W ends at t=30)
    GITER(0, 0, 1, 3, 928, 992, true,  true,  "vmcnt(2)");  // t=28: W29, A31
    GITER(1, 1, 0, 0, 960, 0,   true,  false, "vmcnt(2)");  // t=29: W30
    GITER(2, 0, 1, 0, 992, 0,   true,  false, "vmcnt(0)");  // t=30: W31
    GITER(3, 1, 0, 0, 0,   0,   false, false, "vmcnt(0)");  // t=31
#undef GITER

    // epilogue: C/D layout col=lane&15, row=quad*4+reg
#pragma unroll
    for (int ni = 0; ni < 4; ni++) {
        const int n = bn + wn * 64 + ni * 16 + l16;
        const float bv_ = bias[n];
#pragma unroll
        for (int mi = 0; mi < 4; mi++) {
            const int mbase = bm + wm * 64 + mi * 16 + quad * 4;
            if (mode == 2) {
                const int b_ = mbase >> 11, s0 = mbase & 2047;
                const int h = n >> 6, d = n & 63;
                ushort4v pk_;
#pragma unroll
                for (int r = 0; r < 4; r++)
                    pk_[r] = f2bf((acc[mi][ni][r] + bv_) * scale);
                *(ushort4v*)&((ushort_t*)Cout)[
                    (((size_t)(b_ * 16 + h)) * 64 + d) * 2048 + s0] = pk_;
            } else {
#pragma unroll
                for (int r = 0; r < 4; r++) {
                    const int m = mbase + r;
                    const float of = (acc[mi][ni][r] + bv_) * scale;
                    if (mode == 0) {
                        ((float*)Cout)[(size_t)m * N + n] = of;
                    } else {
                        const int b_ = m >> 11, s = m & 2047;
                        const int h = n >> 6, d = n & 63;
                        ((ushort_t*)Cout)[(((size_t)(b_ * 16 + h)) * 2048 + s) * 64 + d]
                            = f2bf(of);
                    }
                }
            }
        }
    }
}

// fused QKV projections, bf16 A. grid (64, 8, 3): x = M-tile (id%8 XCD reuse).
__global__ __launch_bounds__(256, 3) void gemm_qkv(
    const ushort_t* __restrict__ Qb, const ushort_t* __restrict__ Kb,
    const ushort_t* __restrict__ Vb, const ushort_t* __restrict__ Wb,
    const float* __restrict__ bq, const float* __restrict__ bk,
    const float* __restrict__ bv,
    ushort_t* __restrict__ Qp, ushort_t* __restrict__ Kp,
    ushort_t* __restrict__ Vtp)
{
    const int z = blockIdx.z;
    const ushort_t* A = (z == 0) ? Qb : (z == 1) ? Kb : Vb;
    const ushort_t* W = Wb + (size_t)z * 1024 * 1024;
    const float* bi = (z == 0) ? bq : (z == 1) ? bk : bv;
    void* C = (z == 0) ? (void*)Qp : (z == 1) ? (void*)Kp : (void*)Vtp;
    const float sc = (z == 0) ? QSCALE : 1.0f;
    const int mode = (z == 2) ? 2 : 1;
    gemm_core(A, W, bi, C, sc, mode);
}

// output projection: X bf16, fp32 out.
__global__ __launch_bounds__(256, 3) void gemm_out(
    const ushort_t* __restrict__ X, const ushort_t* __restrict__ W,
    const float* __restrict__ bo, float* __restrict__ out)
{
    gemm_core(X, W, bo, out, 1.0f, 0);
}

// ---------------------------------------------------------------------------
// Flash attention, transposed: S^T = K Q^T so C-layout lane = q, regs = 4
// consecutive keys. P packed to LDS via ds_write_b64; O^T = V^T P; l via
// ones-MFMA. No-max softmax (Q pre-scaled, log2 domain). Double-buffered K/V
// LDS, one barrier per kt, next tile's g2l16 issued before MFMA phase.
// grid (64, 32): blockIdx.x = bh -> same-bh blocks share id%8 (K/V L2 reuse).
// r3-proven + s_setprio(1) around MFMA clusters (T5).
// ---------------------------------------------------------------------------
__global__ __launch_bounds__(256, 4) void attn(
    const ushort_t* __restrict__ Q,   // [B*H, S, 64] (log2-domain scale)
    const ushort_t* __restrict__ Kk,  // [B*H, S, 64]
    const ushort_t* __restrict__ Vt,  // [B*H, 64, S]
    const u64* __restrict__ mb,       // [B, S, 32] bit-packed mask
    ushort_t* __restrict__ X)         // [B, S, H*64]
{
    constexpr int S = 2048;
    __shared__ alignas(16) ushort_t Ks[2][64 * 64];
    __shared__ alignas(16) ushort_t Vs[2][64 * 64];
    __shared__ alignas(16) ushort_t Ps[4][16 * 64];

    const int tid  = threadIdx.x;
    const int lane = tid & 63;
    const int w    = tid >> 6;
    const int quad = lane >> 4;
    const int l16  = lane & 15;
    const int bh = blockIdx.x;
    const int b  = bh >> 4, h = bh & 15;
    const int qbase = blockIdx.y * 64 + w * 16;
    const int qlane = qbase + l16;

    const int r0 = tid >> 3,         cs0 = ((tid & 7) ^ (r0 & 7)) * 8;
    const int r1 = (tid + 256) >> 3, cs1 = ((tid & 7) ^ (r1 & 7)) * 8;

    const ushort_t* Kst0 = &Kk[((size_t)bh * S + r0) * 64 + cs0];  // +kt*4096
    const ushort_t* Kst1 = &Kk[((size_t)bh * S + r1) * 64 + cs1];
    const ushort_t* Vst0 = &Vt[((size_t)bh * 64 + r0) * S + cs0];  // +kt*64
    const ushort_t* Vst1 = &Vt[((size_t)bh * 64 + r1) * S + cs1];

    const int swz = l16 & 7;
    int kvoff[2][4], pfoff[2], pwoff[4];
#pragma unroll
    for (int ks = 0; ks < 2; ks++) {
        pfoff[ks] = l16 * 64 + (((ks * 4 + quad) ^ swz) * 8);
#pragma unroll
        for (int ni = 0; ni < 4; ni++)
            kvoff[ks][ni] = (ni * 16 + l16) * 64 + (((ks * 4 + quad) ^ swz) * 8);
    }
#pragma unroll
    for (int ni = 0; ni < 4; ni++)
        pwoff[ni] = l16 * 64 + (((ni * 2 + (quad >> 1)) ^ swz) * 8) + (quad & 1) * 4;
    ushort_t* Psw = &Ps[w][0];

    short8 qf[2];
#pragma unroll
    for (int ks = 0; ks < 2; ks++)
        qf[ks] = *(const short8*)&Q[((size_t)bh * S + qlane) * 64 + ks * 32 + quad * 8];

    short8 onesv;
#pragma unroll
    for (int i = 0; i < 8; i++) onesv[i] = (short)0x3F80;  // bf16 1.0

    const u64* mrow = mb + ((size_t)b * S + qlane) * 32;

    floatx4 o[4] = {};
    floatx4 lf = {};

    g2l16(Kst0, &Ks[0][tid * 8]);
    g2l16(Kst1, &Ks[0][(tid + 256) * 8]);
    g2l16(Vst0, &Vs[0][tid * 8]);
    g2l16(Vst1, &Vs[0][(tid + 256) * 8]);
    __syncthreads();

    int cur = 0;
    for (int kt = 0; kt < 32; kt++) {
        if (kt < 31) {
            g2l16(Kst0 + (kt + 1) * 4096, &Ks[cur ^ 1][tid * 8]);
            g2l16(Kst1 + (kt + 1) * 4096, &Ks[cur ^ 1][(tid + 256) * 8]);
            g2l16(Vst0 + (kt + 1) * 64,   &Vs[cur ^ 1][tid * 8]);
            g2l16(Vst1 + (kt + 1) * 64,   &Vs[cur ^ 1][(tid + 256) * 8]);
        }
        const ushort_t* Ksc = &Ks[cur][0];
        const ushort_t* Vsc = &Vs[cur][0];

        floatx4 s[4] = {};
        __builtin_amdgcn_s_setprio(1);
#pragma unroll
        for (int ks = 0; ks < 2; ks++)
#pragma unroll
            for (int ni = 0; ni < 4; ni++)
                s[ni] = __builtin_amdgcn_mfma_f32_16x16x32_bf16(
                    *(const short8*)&Ksc[kvoff[ks][ni]], qf[ks], s[ni], 0, 0, 0);
        __builtin_amdgcn_s_setprio(0);

        const u64 mw = mrow[kt];
#pragma unroll
        for (int ni = 0; ni < 4; ni++) {
            const unsigned int t = (unsigned int)(mw >> (ni * 16 + quad * 4));
#pragma unroll
            for (int r = 0; r < 4; r++)
                s[ni][r] = (t & (1u << r)) ? fexp2(s[ni][r]) : 0.f;
        }

#pragma unroll
        for (int ni = 0; ni < 4; ni++) {
            const unsigned int lo = pk2(s[ni][0], s[ni][1]);
            const unsigned int hi = pk2(s[ni][2], s[ni][3]);
            const unsigned long long dv = ((unsigned long long)hi << 32) | lo;
            *(unsigned long long*)&Psw[pwoff[ni]] = dv;
        }

        __builtin_amdgcn_s_setprio(1);
#pragma unroll
        for (int ks = 0; ks < 2; ks++) {
            const short8 pf = *(const short8*)&Psw[pfoff[ks]];
            lf = __builtin_amdgcn_mfma_f32_16x16x32_bf16(onesv, pf, lf, 0, 0, 0);
#pragma unroll
            for (int ni = 0; ni < 4; ni++)
                o[ni] = __builtin_amdgcn_mfma_f32_16x16x32_bf16(
                    *(const short8*)&Vsc[kvoff[ks][ni]], pf, o[ni], 0, 0, 0);
        }
        __builtin_amdgcn_s_setprio(0);
        __syncthreads();
        cur ^= 1;
    }

    const float inv = 1.0f / lf[0];
#pragma unroll
    for (int ni = 0; ni < 4; ni++) {
        ushort4v pk_;
#pragma unroll
        for (int r = 0; r < 4; r++) pk_[r] = f2bf(o[ni][r] * inv);
        *(ushort4v*)&X[((size_t)b * S + qlane) * 1024 + h * 64 + ni * 16 + quad * 4] = pk_;
    }
}

// ---------------------------------------------------------------------------
extern "C" void kernel_launch(void* const* d_in, const int* in_sizes, int n_in,
                              void* d_out, int out_size, void* d_ws, size_t ws_size,
                              hipStream_t stream) {
    const float* q    = (const float*)d_in[0];
    const float* k    = (const float*)d_in[1];
    const float* v    = (const float*)d_in[2];
    const int*   mask = (const int*)d_in[3];
    const float* wq   = (const float*)d_in[4];
    const float* bq   = (const float*)d_in[5];
    const float* wk   = (const float*)d_in[6];
    const float* bk   = (const float*)d_in[7];
    const float* wv   = (const float*)d_in[8];
    const float* bv   = (const float*)d_in[9];
    const float* wo   = (const float*)d_in[10];
    const float* bo   = (const float*)d_in[11];

    const size_t MB = 1024 * 1024;
    uint8_t* ws = (uint8_t*)d_ws;
    ushort_t* Wb   = (ushort_t*)(ws);              //  8 MB: wq,wk,wv,wo bf16
    u64*      mbits= (u64*)(ws + 8 * MB);          //  2 MB
    ushort_t* Qp   = (ushort_t*)(ws + 10 * MB);    // 16 MB
    ushort_t* Kp   = (ushort_t*)(ws + 26 * MB);    // 16 MB
    ushort_t* Vtp  = (ushort_t*)(ws + 42 * MB);    // 16 MB
    ushort_t* Xp   = (ushort_t*)(ws + 58 * MB);    // 16 MB (Xp after attn)
    ushort_t* Qb   = (ushort_t*)(ws + 58 * MB);    // 16 MB (dead before attn)
    ushort_t* Kb   = (ushort_t*)(ws + 74 * MB);    // 16 MB
    ushort_t* Vb   = (ushort_t*)(ws + 90 * MB);    // 16 MB (total 106 MB)

    dim3 blk(256);

    prep<<<dim3(18432), blk, 0, stream>>>(wq, wk, wv, wo, q, k, v, mask,
                                          Wb, Qb, Kb, Vb, mbits);

    gemm_qkv<<<dim3(64, 8, 3), blk, 0, stream>>>(Qb, Kb, Vb, Wb, bq, bk, bv,
                                                 Qp, Kp, Vtp);

    attn<<<dim3(64, 32), blk, 0, stream>>>(Qp, Kp, Vtp, mbits, Xp);

    gemm_out<<<dim3(64, 8), blk, 0, stream>>>(Xp, Wb + 3 * MB, bo, (float*)d_out);
}